// Round 14
// baseline (112.704 us; speedup 1.0000x reference)
//
#include <hip/hip_runtime.h>
#include <math.h>

#define BLOCK 256
#define NW (BLOCK / 64)

typedef float f32x4 __attribute__((ext_vector_type(4)));

__device__ __forceinline__ float sp(float x) {
    // softplus: max(x,0) + log(1 + exp(-|x|)) — fast intrinsics, huge error budget
    return fmaxf(x, 0.0f) + __logf(1.0f + __expf(-fabsf(x)));
}

// Wave64 inclusive scan (add) on the VALU via DPP (verified rounds 7-13).
__device__ __forceinline__ float wave_scan_f32(float s) {
    s += __int_as_float(__builtin_amdgcn_update_dpp(0, __float_as_int(s), 0x111, 0xf, 0xf, false));
    s += __int_as_float(__builtin_amdgcn_update_dpp(0, __float_as_int(s), 0x112, 0xf, 0xf, false));
    s += __int_as_float(__builtin_amdgcn_update_dpp(0, __float_as_int(s), 0x114, 0xf, 0xf, false));
    s += __int_as_float(__builtin_amdgcn_update_dpp(0, __float_as_int(s), 0x118, 0xf, 0xf, false));
    s += __int_as_float(__builtin_amdgcn_update_dpp(0, __float_as_int(s), 0x142, 0xa, 0xf, false));
    s += __int_as_float(__builtin_amdgcn_update_dpp(0, __float_as_int(s), 0x143, 0xc, 0xf, false));
    return s;
}

// Barrier waiting only on LDS ops (global prefetches stay in flight).
__device__ __forceinline__ void lds_barrier() {
    asm volatile("s_waitcnt lgkmcnt(0)\n\ts_barrier" ::: "memory");
}

__global__ __launch_bounds__(BLOCK) void socnet_kernel(
    const f32x4* __restrict__ X,      // (N, L) of 4-ch float4
    const float*  __restrict__ SC,    // (N, 4)
    const float*  __restrict__ wi1, const float* __restrict__ bi1,
    const float*  __restrict__ wi2, const float* __restrict__ bi2,
    const float*  __restrict__ we1, const float* __restrict__ be1,
    const float*  __restrict__ we2, const float* __restrict__ be2,
    f32x4* __restrict__ Y, int L)
{
    const int n    = blockIdx.x;
    const int t    = threadIdx.x;
    const int wid  = t >> 6;

    const size_t rowoff = (size_t)n * (size_t)L;
    const f32x4* Xr = X + rowoff;
    f32x4*       Yr = Y + rowoff;

    // eta MLP weights (broadcast scalars)
    const float W10 = we1[0], W11 = we1[1], B1 = be1[0];
    const float W2  = we2[0], B2e = be2[0];

    // per-row scalars
    const float Q    = SC[n * 4 + 0];
    const float eta0 = SC[n * 4 + 1];
    const float R    = SC[n * 4 + 2];
    const float S3   = SC[n * 4 + 3];
    const float inv  = eta0 / (3600.0f * Q);

    // soc_init from X[n,0,:]
    const f32x4 x0 = Xr[0];
    const float h0 = sp(wi1[0] * x0.y + wi1[1] * x0.z + wi1[2] * x0.w + wi1[3] * R + bi1[0]);
    const float soc = S3 * (1.0f + (wi2[0] * h0 + bi2[0]));

    // s_obs[b][i] = obs(I,T,U,de) for elements [tile*256 .. tile*256+256] (257 entries)
    __shared__ f32x4 s_obs[2][BLOCK + 1];
    __shared__ f32x4 s_wsum[2][NW];

    f32x4 carry = (f32x4)(0.0f);

    const int ntiles = L / BLOCK;  // 16
    const int Lm1 = L - 1;

    // pipeline registers: xc0=tile k, xc1=tile k+1, xc2=tile k+2 (clamped at tail)
    int p = t;
    f32x4 xc0 = Xr[p];
    f32x4 xc1 = Xr[(p + BLOCK     <= Lm1) ? p + BLOCK     : Lm1];
    f32x4 xc2 = Xr[(p + 2 * BLOCK <= Lm1) ? p + 2 * BLOCK : Lm1];

    // de for own tile-0 element; populate s_obs[0] (tile 0's neighbor table)
    float de0 = W2 * sp(W10 * xc0.y + W11 * xc0.z + B1) + B2e;
    {
        f32x4 ob; ob.x = xc0.y; ob.y = xc0.z; ob.z = xc0.w; ob.w = de0;
        s_obs[0][t] = ob;
        if (t == 0) {
            const float d = W2 * sp(W10 * xc1.y + W11 * xc1.z + B1) + B2e;
            f32x4 ob2; ob2.x = xc1.y; ob2.y = xc1.z; ob2.z = xc1.w; ob2.w = d;
            s_obs[0][BLOCK] = ob2;  // element 256 (tile-0 boundary)
        }
    }
    lds_barrier();

    for (int tile = 0; tile < ntiles; ++tile) {
        // global prefetch tile+3 (stays in flight; lds_barrier doesn't drain vmcnt)
        int ip = p + 3 * BLOCK; if (ip > Lm1) ip = Lm1;
        const f32x4 xc3 = Xr[ip];

        // neighbor obs[p+1] from table written during previous tile (issue early)
        const f32x4 nb = s_obs[tile & 1][t + 1];

        // ahead-compute NEXT tile's obs into the other buffer (one sp per element)
        const float de1 = W2 * sp(W10 * xc1.y + W11 * xc1.z + B1) + B2e;
        {
            f32x4 ob; ob.x = xc1.y; ob.y = xc1.z; ob.z = xc1.w; ob.w = de1;
            s_obs[(tile + 1) & 1][t] = ob;
            if (t == 0) {
                const float d2 = W2 * sp(W10 * xc2.y + W11 * xc2.z + B1) + B2e;
                f32x4 ob2; ob2.x = xc2.y; ob2.y = xc2.z; ob2.z = xc2.w; ob2.w = d2;
                s_obs[(tile + 1) & 1][BLOCK] = ob2;  // element (tile+2)*256
            }
        }

        // inc[p] = (obs[p+1] - obs[p]) * dy
        const float dy = inv * (1.0f + de0) * xc0.y;
        f32x4 inc;
        inc.x = (nb.x - xc0.y) * dy;
        inc.y = (nb.y - xc0.z) * dy;
        inc.z = (nb.z - xc0.w) * dy;
        inc.w = (nb.w - de0)  * dy;

        // 64-lane inclusive scan, 4 fp32 channels, on the VALU
        f32x4 scn;
        scn.x = wave_scan_f32(inc.x);
        scn.y = wave_scan_f32(inc.y);
        scn.z = wave_scan_f32(inc.z);
        scn.w = wave_scan_f32(inc.w);

        if ((t & 63) == 63) s_wsum[tile & 1][wid] = scn;
        lds_barrier();  // fences: s_obs handoff + s_wsum publication

        // exclusive prefix at p = carry + prev-wave totals + (scn - inc)
        f32x4 excl = carry + scn - inc;
        #pragma unroll
        for (int w = 0; w < NW; ++w) {
            const f32x4 ws = s_wsum[tile & 1][w];
            if (w < wid) excl += ws;
            carry += ws;
        }

        // y[p] = soc + exclusive prefix; PLAIN store (A/B vs R11's nontemporal:
        // NT stores appear to cap the write stream ~3 TB/s; fill kernel's plain
        // stores sustain 6.9 TB/s. X stays L3-resident either way.)
        const f32x4 yv = excl + (f32x4)(soc);
        Yr[p] = yv;

        // rotate pipeline
        xc0 = xc1; de0 = de1;
        xc1 = xc2;
        xc2 = xc3;
        p += BLOCK;
    }
}

extern "C" void kernel_launch(void* const* d_in, const int* in_sizes, int n_in,
                              void* d_out, int out_size, void* d_ws, size_t ws_size,
                              hipStream_t stream) {
    const f32x4* X   = (const f32x4*)d_in[0];
    const float* SC  = (const float*)d_in[1];
    const float* wi1 = (const float*)d_in[2];
    const float* bi1 = (const float*)d_in[3];
    const float* wi2 = (const float*)d_in[4];
    const float* bi2 = (const float*)d_in[5];
    const float* we1 = (const float*)d_in[6];
    const float* be1 = (const float*)d_in[7];
    const float* we2 = (const float*)d_in[8];
    const float* be2 = (const float*)d_in[9];
    f32x4* Y = (f32x4*)d_out;

    const int N = in_sizes[1] / 4;           // SC is (N,4)
    const int L = in_sizes[0] / (4 * N);     // X is (N,L,4)

    socnet_kernel<<<N, BLOCK, 0, stream>>>(X, SC, wi1, bi1, wi2, bi2,
                                           we1, be1, we2, be2, Y, L);
}

// Round 16
// 89.650 us; speedup vs baseline: 1.2572x; 1.2572x over previous
//
#include <hip/hip_runtime.h>
#include <math.h>

#define BLOCK 256
#define NW (BLOCK / 64)

typedef float f32x4 __attribute__((ext_vector_type(4)));

__device__ __forceinline__ float sp(float x) {
    // softplus: max(x,0) + log(1 + exp(-|x|)) — fast intrinsics, huge error budget
    return fmaxf(x, 0.0f) + __logf(1.0f + __expf(-fabsf(x)));
}

// Wave64 inclusive scan (add) on the VALU via DPP (verified rounds 7-14).
__device__ __forceinline__ float wave_scan_f32(float s) {
    s += __int_as_float(__builtin_amdgcn_update_dpp(0, __float_as_int(s), 0x111, 0xf, 0xf, false));
    s += __int_as_float(__builtin_amdgcn_update_dpp(0, __float_as_int(s), 0x112, 0xf, 0xf, false));
    s += __int_as_float(__builtin_amdgcn_update_dpp(0, __float_as_int(s), 0x114, 0xf, 0xf, false));
    s += __int_as_float(__builtin_amdgcn_update_dpp(0, __float_as_int(s), 0x118, 0xf, 0xf, false));
    s += __int_as_float(__builtin_amdgcn_update_dpp(0, __float_as_int(s), 0x142, 0xa, 0xf, false));
    s += __int_as_float(__builtin_amdgcn_update_dpp(0, __float_as_int(s), 0x143, 0xc, 0xf, false));
    return s;
}

// Barrier waiting only on LDS ops (global prefetches stay in flight).
__device__ __forceinline__ void lds_barrier() {
    asm volatile("s_waitcnt lgkmcnt(0)\n\ts_barrier" ::: "memory");
}

__global__ __launch_bounds__(BLOCK) void socnet_kernel(
    const f32x4* __restrict__ X,      // (N, L) of 4-ch float4
    const float*  __restrict__ SC,    // (N, 4)
    const float*  __restrict__ wi1, const float* __restrict__ bi1,
    const float*  __restrict__ wi2, const float* __restrict__ bi2,
    const float*  __restrict__ we1, const float* __restrict__ be1,
    const float*  __restrict__ we2, const float* __restrict__ be2,
    f32x4* __restrict__ Y, int L)
{
    const int n    = blockIdx.x;
    const int t    = threadIdx.x;
    const int wid  = t >> 6;

    const size_t rowoff = (size_t)n * (size_t)L;
    const f32x4* Xr = X + rowoff;
    f32x4*       Yr = Y + rowoff;

    // eta MLP weights (broadcast scalars)
    const float W10 = we1[0], W11 = we1[1], B1 = be1[0];
    const float W2  = we2[0], B2e = be2[0];

    // per-row scalars
    const float Q    = SC[n * 4 + 0];
    const float eta0 = SC[n * 4 + 1];
    const float R    = SC[n * 4 + 2];
    const float S3   = SC[n * 4 + 3];
    const float inv  = eta0 / (3600.0f * Q);

    // soc_init from X[n,0,:]
    const f32x4 x0 = Xr[0];
    const float h0 = sp(wi1[0] * x0.y + wi1[1] * x0.z + wi1[2] * x0.w + wi1[3] * R + bi1[0]);
    const float soc = S3 * (1.0f + (wi2[0] * h0 + bi2[0]));

    // s_obs[b][i] = obs(I,T,U,de) for elements [tile*256 .. tile*256+256] (257 entries)
    __shared__ f32x4 s_obs[2][BLOCK + 1];
    __shared__ f32x4 s_wsum[2][NW];

    f32x4 carry = (f32x4)(0.0f);

    const int ntiles = L / BLOCK;  // 16
    const int Lm1 = L - 1;

    // pipeline registers: xc0=tile k, xc1=tile k+1, xc2=tile k+2 (clamped at tail)
    int p = t;
    f32x4 xc0 = Xr[p];
    f32x4 xc1 = Xr[(p + BLOCK     <= Lm1) ? p + BLOCK     : Lm1];
    f32x4 xc2 = Xr[(p + 2 * BLOCK <= Lm1) ? p + 2 * BLOCK : Lm1];

    // de for own tile-0 element; populate s_obs[0] (tile 0's neighbor table)
    float de0 = W2 * sp(W10 * xc0.y + W11 * xc0.z + B1) + B2e;
    {
        f32x4 ob; ob.x = xc0.y; ob.y = xc0.z; ob.z = xc0.w; ob.w = de0;
        s_obs[0][t] = ob;
        if (t == 0) {
            const float d = W2 * sp(W10 * xc1.y + W11 * xc1.z + B1) + B2e;
            f32x4 ob2; ob2.x = xc1.y; ob2.y = xc1.z; ob2.z = xc1.w; ob2.w = d;
            s_obs[0][BLOCK] = ob2;  // element 256 (tile-0 boundary)
        }
    }
    lds_barrier();

    for (int tile = 0; tile < ntiles; ++tile) {
        // global prefetch tile+3 (stays in flight; lds_barrier doesn't drain vmcnt)
        int ip = p + 3 * BLOCK; if (ip > Lm1) ip = Lm1;
        const f32x4 xc3 = Xr[ip];

        // neighbor obs[p+1] from table written during previous tile (issue early)
        const f32x4 nb = s_obs[tile & 1][t + 1];

        // ahead-compute NEXT tile's obs into the other buffer (one sp per element)
        const float de1 = W2 * sp(W10 * xc1.y + W11 * xc1.z + B1) + B2e;
        {
            f32x4 ob; ob.x = xc1.y; ob.y = xc1.z; ob.z = xc1.w; ob.w = de1;
            s_obs[(tile + 1) & 1][t] = ob;
            if (t == 0) {
                const float d2 = W2 * sp(W10 * xc2.y + W11 * xc2.z + B1) + B2e;
                f32x4 ob2; ob2.x = xc2.y; ob2.y = xc2.z; ob2.z = xc2.w; ob2.w = d2;
                s_obs[(tile + 1) & 1][BLOCK] = ob2;  // element (tile+2)*256
            }
        }

        // inc[p] = (obs[p+1] - obs[p]) * dy
        const float dy = inv * (1.0f + de0) * xc0.y;
        f32x4 inc;
        inc.x = (nb.x - xc0.y) * dy;
        inc.y = (nb.y - xc0.z) * dy;
        inc.z = (nb.z - xc0.w) * dy;
        inc.w = (nb.w - de0)  * dy;

        // 64-lane inclusive scan, 4 fp32 channels, on the VALU
        f32x4 scn;
        scn.x = wave_scan_f32(inc.x);
        scn.y = wave_scan_f32(inc.y);
        scn.z = wave_scan_f32(inc.z);
        scn.w = wave_scan_f32(inc.w);

        if ((t & 63) == 63) s_wsum[tile & 1][wid] = scn;
        lds_barrier();  // fences: s_obs handoff + s_wsum publication

        // exclusive prefix at p = carry + prev-wave totals + (scn - inc)
        f32x4 excl = carry + scn - inc;
        #pragma unroll
        for (int w = 0; w < NW; ++w) {
            const f32x4 ws = s_wsum[tile & 1][w];
            if (w < wid) excl += ws;
            carry += ws;
        }

        // y[p] = soc + exclusive prefix; nontemporal store (validated best: keeps
        // X cache-resident; plain stores thrash L2/L3 and regress to 112 µs)
        const f32x4 yv = excl + (f32x4)(soc);
        __builtin_nontemporal_store(yv, &Yr[p]);

        // rotate pipeline
        xc0 = xc1; de0 = de1;
        xc1 = xc2;
        xc2 = xc3;
        p += BLOCK;
    }
}

extern "C" void kernel_launch(void* const* d_in, const int* in_sizes, int n_in,
                              void* d_out, int out_size, void* d_ws, size_t ws_size,
                              hipStream_t stream) {
    const f32x4* X   = (const f32x4*)d_in[0];
    const float* SC  = (const float*)d_in[1];
    const float* wi1 = (const float*)d_in[2];
    const float* bi1 = (const float*)d_in[3];
    const float* wi2 = (const float*)d_in[4];
    const float* bi2 = (const float*)d_in[5];
    const float* we1 = (const float*)d_in[6];
    const float* be1 = (const float*)d_in[7];
    const float* we2 = (const float*)d_in[8];
    const float* be2 = (const float*)d_in[9];
    f32x4* Y = (f32x4*)d_out;

    const int N = in_sizes[1] / 4;           // SC is (N,4)
    const int L = in_sizes[0] / (4 * N);     // X is (N,L,4)

    socnet_kernel<<<N, BLOCK, 0, stream>>>(X, SC, wi1, bi1, wi2, bi2,
                                           we1, be1, we2, be2, Y, L);
}